// Round 2
// baseline (285.881 us; speedup 1.0000x reference)
//
#include <hip/hip_runtime.h>
#include <math.h>

#define BB 64
#define TT 2048
#define DD 512
#define TCH 32            // t-chunks in fused PV pass
#define TC (TT / TCH)     // 64 t per chunk

// ---------------------------------------------------------------------------
// Kernel 1: energy[b,t] = dot(key[b,t,:], query[b,:]); masked -> -inf
// 256 threads = 4 waves per block; each wave computes one (b,t) row.
// Block 0 also zeroes the per-b ticket counters used by the fused PV kernel
// (kernel boundary makes the zeros visible before any PV block runs).
// ---------------------------------------------------------------------------
__global__ __launch_bounds__(256) void energy_kernel(
    const float* __restrict__ q, const float* __restrict__ k,
    const int* __restrict__ mask, float* __restrict__ energy,
    unsigned int* __restrict__ counters) {
  if (blockIdx.x == 0 && threadIdx.x < BB) counters[threadIdx.x] = 0u;

  const int wave = threadIdx.x >> 6;
  const int lane = threadIdx.x & 63;
  const long long row = (long long)blockIdx.x * 4 + wave;  // b*TT + t
  const int b = (int)(row >> 11);

  const float4* kp4 = (const float4*)(k + row * DD);
  const float4* qp4 = (const float4*)(q + (long long)b * DD);

  float4 ka = kp4[lane];
  float4 kb = kp4[lane + 64];
  float4 qa = qp4[lane];
  float4 qb = qp4[lane + 64];

  float s = ka.x * qa.x + ka.y * qa.y + ka.z * qa.z + ka.w * qa.w +
            kb.x * qb.x + kb.y * qb.y + kb.z * qb.z + kb.w * qb.w;

#pragma unroll
  for (int off = 32; off; off >>= 1) s += __shfl_down(s, off, 64);

  if (lane == 0) {
    energy[row] = mask[row] ? -INFINITY : s;
  }
}

// ---------------------------------------------------------------------------
// Kernel 2 (fused): per-b softmax stats (redundant per block, L2-resident)
// + attention output write (tc==0 blocks) + PV chunk partial + last-block
// per-b reduction in fixed tc order (deterministic).
// Grid: (BB, TCH) x 128 threads. Thread tid owns float4 at d = 4*tid.
// ---------------------------------------------------------------------------
__global__ __launch_bounds__(128) void pv_fused(
    const float* __restrict__ energy, const float* __restrict__ v,
    float* __restrict__ attn, float* __restrict__ ctx,
    float* __restrict__ partial, unsigned int* __restrict__ counters) {
  const int b = blockIdx.x;
  const int tc = blockIdx.y;
  const int tid = threadIdx.x;  // 0..127
  const int wave = tid >> 6;
  const int lane = tid & 63;

  __shared__ float sred[2];
  __shared__ unsigned int sticket;

  // ---- softmax stats over energy[b, :]  (2048 floats, 4x float4 per thread)
  const float4* e4 = (const float4*)(energy + b * TT);
  float4 ev[4];
  float m = -INFINITY;
#pragma unroll
  for (int i = 0; i < 4; i++) {
    ev[i] = e4[i * 128 + tid];
    m = fmaxf(m, fmaxf(fmaxf(ev[i].x, ev[i].y), fmaxf(ev[i].z, ev[i].w)));
  }
#pragma unroll
  for (int off = 32; off; off >>= 1) m = fmaxf(m, __shfl_xor(m, off, 64));
  if (lane == 0) sred[wave] = m;
  __syncthreads();
  m = fmaxf(sred[0], sred[1]);
  __syncthreads();  // sred reused for the sum below

  float ssum = 0.f;
#pragma unroll
  for (int i = 0; i < 4; i++) {
    ev[i].x = __expf(ev[i].x - m);
    ev[i].y = __expf(ev[i].y - m);
    ev[i].z = __expf(ev[i].z - m);
    ev[i].w = __expf(ev[i].w - m);
    ssum += ev[i].x + ev[i].y + ev[i].z + ev[i].w;
  }
#pragma unroll
  for (int off = 32; off; off >>= 1) ssum += __shfl_xor(ssum, off, 64);
  if (lane == 0) sred[wave] = ssum;
  __syncthreads();
  ssum = sred[0] + sred[1];
  const float inv = 1.0f / ssum;

  // ---- attention output (one writer block per b)
  if (tc == 0) {
    float4* a4 = (float4*)(attn + b * TT);
#pragma unroll
    for (int i = 0; i < 4; i++) {
      float4 o;
      o.x = ev[i].x * inv; o.y = ev[i].y * inv;
      o.z = ev[i].z * inv; o.w = ev[i].w * inv;
      a4[i * 128 + tid] = o;
    }
  }

  // ---- PV chunk: t in [tc*TC, tc*TC+TC)
  const float* ep = energy + b * TT + tc * TC;
  const float4* vp = (const float4*)(v + ((long long)b * TT + (long long)tc * TC) * DD);

  float4 acc = {0.f, 0.f, 0.f, 0.f};
#pragma unroll 8
  for (int t = 0; t < TC; t++) {
    const float a = __expf(ep[t] - m) * inv;
    const float4 vv = vp[t * 128 + tid];
    acc.x += a * vv.x;
    acc.y += a * vv.y;
    acc.z += a * vv.z;
    acc.w += a * vv.w;
  }

  float4* p4 = (float4*)partial;
  p4[(b * TCH + tc) * 128 + tid] = acc;

  // ---- last-block-per-b reduction (fixed order => deterministic)
  __threadfence();   // release: make partial visible device-wide
  __syncthreads();
  if (tid == 0) sticket = atomicAdd(&counters[b], 1u);
  __syncthreads();
  if (sticket == TCH - 1) {
    __threadfence();  // acquire: invalidate stale lines before reading partials
    float4 s = {0.f, 0.f, 0.f, 0.f};
#pragma unroll
    for (int j = 0; j < TCH; j++) {
      const float4 pv = p4[(b * TCH + j) * 128 + tid];
      s.x += pv.x; s.y += pv.y; s.z += pv.z; s.w += pv.w;
    }
    ((float4*)ctx)[b * 128 + tid] = s;
  }
}

// ---------------------------------------------------------------------------
extern "C" void kernel_launch(void* const* d_in, const int* in_sizes, int n_in,
                              void* d_out, int out_size, void* d_ws, size_t ws_size,
                              hipStream_t stream) {
  const float* q    = (const float*)d_in[0];  // [B,D]
  const float* k    = (const float*)d_in[1];  // [B,T,D]
  const float* v    = (const float*)d_in[2];  // [B,T,D]
  const int*   mask = (const int*)d_in[3];    // [B,T], 0/1

  float* out  = (float*)d_out;
  float* ctx  = out;            // [B,D]   first output
  float* attn = out + BB * DD;  // [B,T]   second output

  float*        energy   = (float*)d_ws;                 // B*T floats  = 512 KB
  float*        partial  = energy + BB * TT;             // B*TCH*D fl  = 4 MB
  unsigned int* counters = (unsigned int*)(partial + BB * TCH * DD);  // 64 u32

  energy_kernel<<<BB * TT / 4, 256, 0, stream>>>(q, k, mask, energy, counters);
  pv_fused<<<dim3(BB, TCH), 128, 0, stream>>>(energy, v, attn, ctx, partial, counters);
}

// Round 3
// 99.242 us; speedup vs baseline: 2.8807x; 2.8807x over previous
//
#include <hip/hip_runtime.h>
#include <math.h>

#define BB 64
#define TT 2048
#define DD 512
#define TCH 16            // t-chunks in fused PV pass
#define TC (TT / TCH)     // 128 t per chunk (== blockDim of pv_fused)

// ---------------------------------------------------------------------------
// Kernel 1: energy[b,t] = dot(key[b,t,:], query[b,:]); masked -> -inf
// 256 threads = 4 waves per block; each wave computes one (b,t) row.
// ---------------------------------------------------------------------------
__global__ __launch_bounds__(256) void energy_kernel(
    const float* __restrict__ q, const float* __restrict__ k,
    const int* __restrict__ mask, float* __restrict__ energy) {
  const int wave = threadIdx.x >> 6;
  const int lane = threadIdx.x & 63;
  const long long row = (long long)blockIdx.x * 4 + wave;  // b*TT + t
  const int b = (int)(row >> 11);

  const float4* kp4 = (const float4*)(k + row * DD);
  const float4* qp4 = (const float4*)(q + (long long)b * DD);

  float4 ka = kp4[lane];
  float4 kb = kp4[lane + 64];
  float4 qa = qp4[lane];
  float4 qb = qp4[lane + 64];

  float s = ka.x * qa.x + ka.y * qa.y + ka.z * qa.z + ka.w * qa.w +
            kb.x * qb.x + kb.y * qb.y + kb.z * qb.z + kb.w * qb.w;

#pragma unroll
  for (int off = 32; off; off >>= 1) s += __shfl_down(s, off, 64);

  if (lane == 0) {
    energy[row] = mask[row] ? -INFINITY : s;
  }
}

// ---------------------------------------------------------------------------
// Kernel 2 (fused): per-b softmax stats (redundant per block, energy row is
// L2-resident) + attention output write (tc==0 blocks) + PV chunk partial.
// NO cross-block communication: no fences, no atomics (round-2 post-mortem:
// per-block agent-scope fences serialized at the TCC -> 244us).
// Grid: (BB, TCH) x 128 threads. Thread tid owns float4 at d = 4*tid.
// ---------------------------------------------------------------------------
__global__ __launch_bounds__(128) void pv_fused(
    const float* __restrict__ energy, const float* __restrict__ v,
    float* __restrict__ attn, float* __restrict__ partial) {
  const int b = blockIdx.x;
  const int tc = blockIdx.y;
  const int tid = threadIdx.x;  // 0..127
  const int wave = tid >> 6;
  const int lane = tid & 63;

  __shared__ float sred[2];
  __shared__ float sa[TC];

  // ---- softmax stats over energy[b, :]  (2048 floats, 4x float4 per thread)
  const float4* e4 = (const float4*)(energy + b * TT);
  float4 ev[4];
  float m = -INFINITY;
#pragma unroll
  for (int i = 0; i < 4; i++) {
    ev[i] = e4[i * 128 + tid];
    m = fmaxf(m, fmaxf(fmaxf(ev[i].x, ev[i].y), fmaxf(ev[i].z, ev[i].w)));
  }
#pragma unroll
  for (int off = 32; off; off >>= 1) m = fmaxf(m, __shfl_xor(m, off, 64));
  if (lane == 0) sred[wave] = m;
  __syncthreads();
  m = fmaxf(sred[0], sred[1]);
  __syncthreads();  // sred reused for the sum below

  float ssum = 0.f;
#pragma unroll
  for (int i = 0; i < 4; i++) {
    ev[i].x = __expf(ev[i].x - m);
    ev[i].y = __expf(ev[i].y - m);
    ev[i].z = __expf(ev[i].z - m);
    ev[i].w = __expf(ev[i].w - m);
    ssum += ev[i].x + ev[i].y + ev[i].z + ev[i].w;
  }
#pragma unroll
  for (int off = 32; off; off >>= 1) ssum += __shfl_xor(ssum, off, 64);
  if (lane == 0) sred[wave] = ssum;
  __syncthreads();
  ssum = sred[0] + sred[1];
  const float inv = 1.0f / ssum;

  // ---- attention output (one writer block per b; regs already hold the row)
  if (tc == 0) {
    float4* a4 = (float4*)(attn + b * TT);
#pragma unroll
    for (int i = 0; i < 4; i++) {
      float4 o;
      o.x = ev[i].x * inv; o.y = ev[i].y * inv;
      o.z = ev[i].z * inv; o.w = ev[i].w * inv;
      a4[i * 128 + tid] = o;
    }
  }

  // ---- chunk weights into LDS (one expf per t, not per thread*t)
  const float* ep = energy + b * TT + tc * TC;
  sa[tid] = __expf(ep[tid] - m) * inv;  // TC == blockDim == 128
  __syncthreads();

  // ---- PV chunk: pure V stream; a[t] is an LDS broadcast (conflict-free)
  const float4* vp = (const float4*)(v + ((long long)b * TT + (long long)tc * TC) * DD);
  float4 acc = {0.f, 0.f, 0.f, 0.f};
#pragma unroll 8
  for (int t = 0; t < TC; t++) {
    const float a = sa[t];
    const float4 vv = vp[t * 128 + tid];
    acc.x += a * vv.x;
    acc.y += a * vv.y;
    acc.z += a * vv.z;
    acc.w += a * vv.w;
  }
  ((float4*)partial)[(b * TCH + tc) * 128 + tid] = acc;
}

// ---------------------------------------------------------------------------
// Kernel 3: context[b,d] = sum_tc partial[b,tc,d]  (2 MB, L2-resident)
// One thread per float4 of context: B*D/4 = 8192 threads = 32 blocks.
// ---------------------------------------------------------------------------
__global__ __launch_bounds__(256) void pv_reduce(
    const float* __restrict__ partial, float* __restrict__ ctx) {
  const int i = blockIdx.x * 256 + threadIdx.x;  // over B*128 float4s
  const int b = i >> 7;
  const int d4 = i & 127;
  const float4* p4 = (const float4*)partial;
  float4 s = {0.f, 0.f, 0.f, 0.f};
#pragma unroll
  for (int tc = 0; tc < TCH; tc++) {
    const float4 p = p4[(b * TCH + tc) * 128 + d4];
    s.x += p.x; s.y += p.y; s.z += p.z; s.w += p.w;
  }
  ((float4*)ctx)[i] = s;
}

// ---------------------------------------------------------------------------
extern "C" void kernel_launch(void* const* d_in, const int* in_sizes, int n_in,
                              void* d_out, int out_size, void* d_ws, size_t ws_size,
                              hipStream_t stream) {
  const float* q    = (const float*)d_in[0];  // [B,D]
  const float* k    = (const float*)d_in[1];  // [B,T,D]
  const float* v    = (const float*)d_in[2];  // [B,T,D]
  const int*   mask = (const int*)d_in[3];    // [B,T], 0/1

  float* out  = (float*)d_out;
  float* ctx  = out;            // [B,D]   first output
  float* attn = out + BB * DD;  // [B,T]   second output

  float* energy  = (float*)d_ws;        // B*T floats   = 512 KB
  float* partial = energy + BB * TT;    // B*TCH*D fl   = 2 MB

  energy_kernel<<<BB * TT / 4, 256, 0, stream>>>(q, k, mask, energy);
  pv_fused<<<dim3(BB, TCH), 128, 0, stream>>>(energy, v, attn, partial);
  pv_reduce<<<BB * DD / 4 / 256, 256, 0, stream>>>(partial, ctx);
}